// Round 3
// baseline (585.595 us; speedup 1.0000x reference)
//
#include <hip/hip_runtime.h>

#define D 128
typedef unsigned int uint;
typedef unsigned short ushort;

// round-to-nearest-even f32 -> bf16 (bit trick, no header dependency)
__device__ __forceinline__ ushort f2bf(float f) {
    uint u = __float_as_uint(f);
    u += 0x7fffu + ((u >> 16) & 1u);
    return (ushort)(u >> 16);
}

// ---------------- CSR build ----------------

__global__ void hist_k(const int* __restrict__ tgt, int* __restrict__ cnt, int E) {
    int i = blockIdx.x * blockDim.x + threadIdx.x;
    if (i < E) atomicAdd(&cnt[tgt[i]], 1);
}

__global__ void scan_k(const int* __restrict__ cnt, int* __restrict__ row_ptr, int n) {
    __shared__ int lds[1024];
    int t = threadIdx.x;
    int seg = (n + 1023) / 1024;
    int lo = t * seg, hi = lo + seg;
    if (hi > n) hi = n;
    if (lo > n) lo = n;
    int s = 0;
    for (int i = lo; i < hi; ++i) s += cnt[i];
    lds[t] = s;
    __syncthreads();
    for (int off = 1; off < 1024; off <<= 1) {
        int v = (t >= off) ? lds[t - off] : 0;
        __syncthreads();
        lds[t] += v;
        __syncthreads();
    }
    int excl = lds[t] - s;
    for (int i = lo; i < hi; ++i) { row_ptr[i] = excl; excl += cnt[i]; }
    if (t == 1023) row_ptr[n] = lds[1023];
}

__global__ void fill_k(const int* __restrict__ src, const int* __restrict__ tgt,
                       const int* __restrict__ row_ptr, int* __restrict__ cur,
                       int* __restrict__ srcs, int E) {
    int i = blockIdx.x * blockDim.x + threadIdx.x;
    if (i < E) {
        int tg = tgt[i];
        int p = row_ptr[tg] + atomicAdd(&cur[tg], 1);
        srcs[p] = src[i];
    }
}

// ---------------- f32 -> bf16 convert ----------------

__global__ __launch_bounds__(256) void cvt_k(const float* __restrict__ in,
                                             ushort* __restrict__ out, int n4) {
    int i = blockIdx.x * 256 + threadIdx.x;
    if (i < n4) {
        float4 a = reinterpret_cast<const float4*>(in)[i];
        ushort4 o;
        o.x = f2bf(a.x); o.y = f2bf(a.y); o.z = f2bf(a.z); o.w = f2bf(a.w);
        reinterpret_cast<ushort4*>(out)[i] = o;
    }
}

// ---------------- mean aggregation (CSR gather, bf16 rows, f32 accum) -------
// block = 256 threads = 4 waves, one node per wave.
// Within a wave: g = lane>>4 picks one of 4 edges in flight; l = lane&15 reads
// 16B (8 bf16 features). Final butterfly across g groups.

__global__ __launch_bounds__(256) void aggr_k(const ushort* __restrict__ Xb,
                                              const int* __restrict__ srcs,
                                              const int* __restrict__ row_ptr,
                                              float* __restrict__ aggr, int N) {
    int node = blockIdx.x * 4 + (threadIdx.x >> 6);
    if (node >= N) return;
    int lane = threadIdx.x & 63;
    int g = lane >> 4, l = lane & 15;
    int lo = row_ptr[node], hi = row_ptr[node + 1];
    float acc[8] = {0.f, 0.f, 0.f, 0.f, 0.f, 0.f, 0.f, 0.f};
    for (int base = lo; base < hi; base += 64) {
        int idx = base + lane;
        int sv = (idx < hi) ? srcs[idx] : -1;
        int cnt = min(64, hi - base);
        for (int e = 0; e < cnt; e += 4) {
            int s = __shfl(sv, e + g);
            if (s >= 0) {
                const uint4 v = *reinterpret_cast<const uint4*>(Xb + (size_t)s * D + l * 8);
                acc[0] += __uint_as_float(v.x << 16);
                acc[1] += __uint_as_float(v.x & 0xffff0000u);
                acc[2] += __uint_as_float(v.y << 16);
                acc[3] += __uint_as_float(v.y & 0xffff0000u);
                acc[4] += __uint_as_float(v.z << 16);
                acc[5] += __uint_as_float(v.z & 0xffff0000u);
                acc[6] += __uint_as_float(v.w << 16);
                acc[7] += __uint_as_float(v.w & 0xffff0000u);
            }
        }
    }
#pragma unroll
    for (int j = 0; j < 8; ++j) {
        acc[j] += __shfl_xor(acc[j], 16);
        acc[j] += __shfl_xor(acc[j], 32);
    }
    if (g == 0) {
        float inv = 1.0f / fmaxf((float)(hi - lo), 1.0f);
        float4 r0 = {acc[0] * inv, acc[1] * inv, acc[2] * inv, acc[3] * inv};
        float4 r1 = {acc[4] * inv, acc[5] * inv, acc[6] * inv, acc[7] * inv};
        float* dst = aggr + (size_t)node * D + l * 8;
        *reinterpret_cast<float4*>(dst) = r0;
        *reinterpret_cast<float4*>(dst + 4) = r1;
    }
}

// ---------------- fused concat-GEMM + bias + relu ----------------
// block tile: 64 nodes x 128 cols. thread: 8 nodes x 4 cols.
// jg = t&31 -> cols j0..j0+3 ; mg = t>>5 -> nodes node0..node0+7.
// Optionally writes a bf16 copy of the output (for next layer's gather).

__global__ __launch_bounds__(256) void gemm_k(
    const float* __restrict__ X, const float* __restrict__ A,
    const float* __restrict__ W, const float* __restrict__ bias,
    float* __restrict__ out, ushort* __restrict__ out_bf, int n) {
    int jg = threadIdx.x & 31;
    int mg = threadIdx.x >> 5;
    int j0 = jg * 4;
    int node0 = blockIdx.x * 64 + mg * 8;
    int roff[8];
#pragma unroll
    for (int i = 0; i < 8; ++i) {
        int nd = node0 + i;
        if (nd > n - 1) nd = n - 1;  // clamp (last block only)
        roff[i] = nd * D;
    }
    float acc[8][4];
#pragma unroll
    for (int i = 0; i < 8; ++i)
        acc[i][0] = acc[i][1] = acc[i][2] = acc[i][3] = 0.f;

#pragma unroll
    for (int half = 0; half < 2; ++half) {
        const float* __restrict__ R = half ? A : X;
        const float* __restrict__ Wh = W + half * D * D;
        for (int k = 0; k < D; k += 4) {
            float4 w0 = *reinterpret_cast<const float4*>(Wh + (k + 0) * D + j0);
            float4 w1 = *reinterpret_cast<const float4*>(Wh + (k + 1) * D + j0);
            float4 w2 = *reinterpret_cast<const float4*>(Wh + (k + 2) * D + j0);
            float4 w3 = *reinterpret_cast<const float4*>(Wh + (k + 3) * D + j0);
#pragma unroll
            for (int i = 0; i < 8; ++i) {
                float4 xv = *reinterpret_cast<const float4*>(R + roff[i] + k);
                acc[i][0] += xv.x * w0.x + xv.y * w1.x + xv.z * w2.x + xv.w * w3.x;
                acc[i][1] += xv.x * w0.y + xv.y * w1.y + xv.z * w2.y + xv.w * w3.y;
                acc[i][2] += xv.x * w0.z + xv.y * w1.z + xv.z * w2.z + xv.w * w3.z;
                acc[i][3] += xv.x * w0.w + xv.y * w1.w + xv.z * w2.w + xv.w * w3.w;
            }
        }
    }
    float4 b4 = *reinterpret_cast<const float4*>(bias + j0);
    // in-place safety for layer 2: all k-loop reads of this block's rows
    // complete before any store from this block.
    __syncthreads();
#pragma unroll
    for (int i = 0; i < 8; ++i) {
        int nd = node0 + i;
        if (nd < n) {
            float4 r;
            r.x = fmaxf(acc[i][0] + b4.x, 0.f);
            r.y = fmaxf(acc[i][1] + b4.y, 0.f);
            r.z = fmaxf(acc[i][2] + b4.z, 0.f);
            r.w = fmaxf(acc[i][3] + b4.w, 0.f);
            *reinterpret_cast<float4*>(out + (size_t)nd * D + j0) = r;
            if (out_bf) {
                ushort4 o;
                o.x = f2bf(r.x); o.y = f2bf(r.y); o.z = f2bf(r.z); o.w = f2bf(r.w);
                reinterpret_cast<ushort4*>(out_bf + (size_t)nd * D)[jg] = o;
            }
        }
    }
}

extern "C" void kernel_launch(void* const* d_in, const int* in_sizes, int n_in,
                              void* d_out, int out_size, void* d_ws, size_t ws_size,
                              hipStream_t stream) {
    const float* x  = (const float*)d_in[0];
    const int*   ei = (const int*)d_in[1];
    const float* W1 = (const float*)d_in[2];
    const float* b1 = (const float*)d_in[3];
    const float* W2 = (const float*)d_in[4];
    const float* b2 = (const float*)d_in[5];
    float* out = (float*)d_out;

    const int N = in_sizes[0] / D;  // 50000
    const int E = in_sizes[1] / 2;  // 800000
    const int* src = ei;
    const int* tgt = ei + E;

    char* w = (char*)d_ws;
    auto alloc = [&](size_t bytes) -> char* {
        char* p = w;
        w += ((bytes + 255) / 256) * 256;
        return p;
    };
    int*    row_ptr = (int*)alloc((size_t)(N + 1) * 4);
    int*    cnt     = (int*)alloc((size_t)N * 4);
    int*    srcs    = (int*)alloc((size_t)E * 4);
    float*  aggr    = (float*)alloc((size_t)N * D * 4);
    ushort* xb      = (ushort*)alloc((size_t)N * D * 2);  // x bf16, later reused for h1 bf16

    // ---- CSR build (shared by both layers) ----
    hipMemsetAsync(cnt, 0, (size_t)N * sizeof(int), stream);
    hist_k<<<(E + 255) / 256, 256, 0, stream>>>(tgt, cnt, E);
    scan_k<<<1, 1024, 0, stream>>>(cnt, row_ptr, N);
    hipMemsetAsync(cnt, 0, (size_t)N * sizeof(int), stream);
    fill_k<<<(E + 255) / 256, 256, 0, stream>>>(src, tgt, row_ptr, cnt, srcs, E);

    // ---- bf16 copy of x for the gather ----
    cvt_k<<<(N * D / 4 + 255) / 256, 256, 0, stream>>>(x, xb, N * D / 4);

    // ---- layer 1 ----
    aggr_k<<<(N + 3) / 4, 256, 0, stream>>>(xb, srcs, row_ptr, aggr, N);
    // writes h1 (f32) to out and h1 (bf16) over xb for layer-2 gather
    gemm_k<<<(N + 63) / 64, 256, 0, stream>>>(x, aggr, W1, b1, out, xb, N);

    // ---- layer 2 (gemm safely in-place on out) ----
    aggr_k<<<(N + 3) / 4, 256, 0, stream>>>(xb, srcs, row_ptr, aggr, N);
    gemm_k<<<(N + 63) / 64, 256, 0, stream>>>(out, aggr, W2, b2, out, nullptr, N);
}

// Round 4
// 344.160 us; speedup vs baseline: 1.7015x; 1.7015x over previous
//
#include <hip/hip_runtime.h>

#define D 128
typedef unsigned int uint;
typedef unsigned short ushort;
typedef __attribute__((ext_vector_type(8))) __bf16 bf16x8;
typedef __attribute__((ext_vector_type(4))) float f32x4;

// round-to-nearest-even f32 -> bf16 (bit trick)
__device__ __forceinline__ ushort f2bf(float f) {
    uint u = __float_as_uint(f);
    u += 0x7fffu + ((u >> 16) & 1u);
    return (ushort)(u >> 16);
}

// ---------------- CSR build ----------------

__global__ void hist_k(const int* __restrict__ tgt, int* __restrict__ cnt, int E) {
    int i = blockIdx.x * blockDim.x + threadIdx.x;
    if (i < E) atomicAdd(&cnt[tgt[i]], 1);
}

__global__ void scan_k(const int* __restrict__ cnt, int* __restrict__ row_ptr, int n) {
    __shared__ int lds[1024];
    int t = threadIdx.x;
    int seg = (n + 1023) / 1024;
    int lo = t * seg, hi = lo + seg;
    if (hi > n) hi = n;
    if (lo > n) lo = n;
    int s = 0;
    for (int i = lo; i < hi; ++i) s += cnt[i];
    lds[t] = s;
    __syncthreads();
    for (int off = 1; off < 1024; off <<= 1) {
        int v = (t >= off) ? lds[t - off] : 0;
        __syncthreads();
        lds[t] += v;
        __syncthreads();
    }
    int excl = lds[t] - s;
    for (int i = lo; i < hi; ++i) { row_ptr[i] = excl; excl += cnt[i]; }
    if (t == 1023) row_ptr[n] = lds[1023];
}

__global__ void fill_k(const int* __restrict__ src, const int* __restrict__ tgt,
                       const int* __restrict__ row_ptr, int* __restrict__ cur,
                       int* __restrict__ srcs, int E) {
    int i = blockIdx.x * blockDim.x + threadIdx.x;
    if (i < E) {
        int tg = tgt[i];
        int p = row_ptr[tg] + atomicAdd(&cur[tg], 1);
        srcs[p] = src[i];
    }
}

// ---------------- f32 -> bf16 convert ----------------

__global__ __launch_bounds__(256) void cvt_k(const float* __restrict__ in,
                                             ushort* __restrict__ out, int n4) {
    int i = blockIdx.x * 256 + threadIdx.x;
    if (i < n4) {
        float4 a = reinterpret_cast<const float4*>(in)[i];
        ushort4 o;
        o.x = f2bf(a.x); o.y = f2bf(a.y); o.z = f2bf(a.z); o.w = f2bf(a.w);
        reinterpret_cast<ushort4*>(out)[i] = o;
    }
}

// ---------------- W pack into MFMA B-fragment order ----------------
// entry (ks, ct, lane): wp[((ks*8+ct)*64+lane)*8 + e] =
//   bf16( W[ks*32 + (lane>>4)*8 + e][ct*16 + (lane&15)] )
// so the gemm's B-frag load is one coalesced dwordx4 per lane.

__global__ __launch_bounds__(256) void pack_k(const float* __restrict__ W,
                                              ushort* __restrict__ wp) {
    int idx = blockIdx.x * 256 + threadIdx.x;  // 0 .. 4095
    if (idx >= 8 * 8 * 64) return;
    int lane = idx & 63;
    int ct = (idx >> 6) & 7;
    int ks = idx >> 9;
    int col = ct * 16 + (lane & 15);
    int k0 = ks * 32 + (lane >> 4) * 8;
    ushort v[8];
#pragma unroll
    for (int e = 0; e < 8; ++e) v[e] = f2bf(W[(size_t)(k0 + e) * D + col]);
    ushort4 lo4; lo4.x = v[0]; lo4.y = v[1]; lo4.z = v[2]; lo4.w = v[3];
    ushort4 hi4; hi4.x = v[4]; hi4.y = v[5]; hi4.z = v[6]; hi4.w = v[7];
    reinterpret_cast<ushort4*>(wp + (size_t)idx * 8)[0] = lo4;
    reinterpret_cast<ushort4*>(wp + (size_t)idx * 8)[1] = hi4;
}

// ---------------- mean aggregation (CSR gather, bf16 rows, f32 accum) -------
// block = 256 threads = 4 waves, one node per wave; 4 edges in flight
// (g = lane>>4), 16 lanes x 16B per row; bf16 output.

__global__ __launch_bounds__(256) void aggr_k(const ushort* __restrict__ Xb,
                                              const int* __restrict__ srcs,
                                              const int* __restrict__ row_ptr,
                                              ushort* __restrict__ aggr, int N) {
    int node = blockIdx.x * 4 + (threadIdx.x >> 6);
    if (node >= N) return;
    int lane = threadIdx.x & 63;
    int g = lane >> 4, l = lane & 15;
    int lo = row_ptr[node], hi = row_ptr[node + 1];
    float acc[8] = {0.f, 0.f, 0.f, 0.f, 0.f, 0.f, 0.f, 0.f};
    for (int base = lo; base < hi; base += 64) {
        int idx = base + lane;
        int sv = (idx < hi) ? srcs[idx] : -1;
        int cnt = min(64, hi - base);
        for (int e = 0; e < cnt; e += 4) {
            int s = __shfl(sv, e + g);
            if (s >= 0) {
                const uint4 v = *reinterpret_cast<const uint4*>(Xb + (size_t)s * D + l * 8);
                acc[0] += __uint_as_float(v.x << 16);
                acc[1] += __uint_as_float(v.x & 0xffff0000u);
                acc[2] += __uint_as_float(v.y << 16);
                acc[3] += __uint_as_float(v.y & 0xffff0000u);
                acc[4] += __uint_as_float(v.z << 16);
                acc[5] += __uint_as_float(v.z & 0xffff0000u);
                acc[6] += __uint_as_float(v.w << 16);
                acc[7] += __uint_as_float(v.w & 0xffff0000u);
            }
        }
    }
#pragma unroll
    for (int j = 0; j < 8; ++j) {
        acc[j] += __shfl_xor(acc[j], 16);
        acc[j] += __shfl_xor(acc[j], 32);
    }
    if (g == 0) {
        float inv = 1.0f / fmaxf((float)(hi - lo), 1.0f);
        ushort4 o0, o1;
        o0.x = f2bf(acc[0] * inv); o0.y = f2bf(acc[1] * inv);
        o0.z = f2bf(acc[2] * inv); o0.w = f2bf(acc[3] * inv);
        o1.x = f2bf(acc[4] * inv); o1.y = f2bf(acc[5] * inv);
        o1.z = f2bf(acc[6] * inv); o1.w = f2bf(acc[7] * inv);
        ushort* dst = aggr + (size_t)node * D + l * 8;
        reinterpret_cast<ushort4*>(dst)[0] = o0;
        reinterpret_cast<ushort4*>(dst)[1] = o1;
    }
}

// ---------------- MFMA concat-GEMM + bias + relu ----------------
// C[n][128] = relu( concat(Xb,Ab)[n][256] @ W + b ),  bf16 inputs, f32 acc.
// Block = 256 thr = 4 waves. Wave w: rows [blk*64+(w&1)*32, +32),
// col tiles ct0=(w>>1)*4 .. +4 (64 cols). 8 k-steps of 32 (4 from Xb, 4 from Ab).
// mfma_f32_16x16x32_bf16: A/B frag = 8 contiguous-k bf16 at row/col=lane&15,
// k0=(lane>>4)*8; C/D col=lane&15, row=(lane>>4)*4+reg.

__global__ __launch_bounds__(256) void gemm_k(
    const ushort* __restrict__ Xb, const ushort* __restrict__ Ab,
    const ushort* __restrict__ Wp, const float* __restrict__ bias,
    float* __restrict__ outf, ushort* __restrict__ outb, int n) {
    int lane = threadIdx.x & 63;
    int w = threadIdx.x >> 6;
    int row_base = blockIdx.x * 64 + (w & 1) * 32;
    int ct0 = (w >> 1) * 4;
    int r0 = row_base + (lane & 15);
    int r1 = row_base + 16 + (lane & 15);
    if (r0 > n - 1) r0 = n - 1;
    if (r1 > n - 1) r1 = n - 1;
    int klo = (lane >> 4) * 8;

    f32x4 acc[2][4] = {};
#pragma unroll
    for (int ks = 0; ks < 8; ++ks) {
        const ushort* __restrict__ S = (ks < 4) ? Xb : Ab;
        int koff = (ks & 3) * 32 + klo;
        bf16x8 a0 = *reinterpret_cast<const bf16x8*>(S + (size_t)r0 * D + koff);
        bf16x8 a1 = *reinterpret_cast<const bf16x8*>(S + (size_t)r1 * D + koff);
        const ushort* wb = Wp + ((size_t)(ks * 8 + ct0) * 64 + lane) * 8;
#pragma unroll
        for (int c = 0; c < 4; ++c) {
            bf16x8 b = *reinterpret_cast<const bf16x8*>(wb + (size_t)c * 64 * 8);
            acc[0][c] = __builtin_amdgcn_mfma_f32_16x16x32_bf16(a0, b, acc[0][c], 0, 0, 0);
            acc[1][c] = __builtin_amdgcn_mfma_f32_16x16x32_bf16(a1, b, acc[1][c], 0, 0, 0);
        }
    }

    int cw = lane & 15;
    int rq = lane >> 4;
#pragma unroll
    for (int rt = 0; rt < 2; ++rt) {
#pragma unroll
        for (int c = 0; c < 4; ++c) {
            int col = (ct0 + c) * 16 + cw;
            float bv = bias[col];
#pragma unroll
            for (int r = 0; r < 4; ++r) {
                int node = row_base + rt * 16 + rq * 4 + r;
                if (node < n) {
                    float v = fmaxf(acc[rt][c][r] + bv, 0.f);
                    if (outf) outf[(size_t)node * D + col] = v;
                    if (outb) outb[(size_t)node * D + col] = f2bf(v);
                }
            }
        }
    }
}

extern "C" void kernel_launch(void* const* d_in, const int* in_sizes, int n_in,
                              void* d_out, int out_size, void* d_ws, size_t ws_size,
                              hipStream_t stream) {
    const float* x  = (const float*)d_in[0];
    const int*   ei = (const int*)d_in[1];
    const float* W1 = (const float*)d_in[2];
    const float* b1 = (const float*)d_in[3];
    const float* W2 = (const float*)d_in[4];
    const float* b2 = (const float*)d_in[5];
    float* out = (float*)d_out;

    const int N = in_sizes[0] / D;  // 50000
    const int E = in_sizes[1] / 2;  // 800000
    const int* src = ei;
    const int* tgt = ei + E;

    char* w = (char*)d_ws;
    auto alloc = [&](size_t bytes) -> char* {
        char* p = w;
        w += ((bytes + 255) / 256) * 256;
        return p;
    };
    int*    row_ptr = (int*)alloc((size_t)(N + 1) * 4);
    int*    cnt     = (int*)alloc((size_t)N * 4);
    int*    srcs    = (int*)alloc((size_t)E * 4);
    ushort* xb      = (ushort*)alloc((size_t)N * D * 2);  // x   bf16
    ushort* h1b     = (ushort*)alloc((size_t)N * D * 2);  // h1  bf16
    ushort* ab      = (ushort*)alloc((size_t)N * D * 2);  // aggr bf16 (both layers)
    ushort* wp1     = (ushort*)alloc((size_t)8 * 8 * 64 * 8 * 2);
    ushort* wp2     = (ushort*)alloc((size_t)8 * 8 * 64 * 8 * 2);

    // ---- CSR build (shared by both layers) ----
    hipMemsetAsync(cnt, 0, (size_t)N * sizeof(int), stream);
    hist_k<<<(E + 255) / 256, 256, 0, stream>>>(tgt, cnt, E);
    scan_k<<<1, 1024, 0, stream>>>(cnt, row_ptr, N);
    hipMemsetAsync(cnt, 0, (size_t)N * sizeof(int), stream);
    fill_k<<<(E + 255) / 256, 256, 0, stream>>>(src, tgt, row_ptr, cnt, srcs, E);

    // ---- bf16 conversions / weight packing ----
    cvt_k<<<(N * D / 4 + 255) / 256, 256, 0, stream>>>(x, xb, N * D / 4);
    pack_k<<<16, 256, 0, stream>>>(W1, wp1);
    pack_k<<<16, 256, 0, stream>>>(W2, wp2);

    // ---- layer 1 ----
    aggr_k<<<(N + 3) / 4, 256, 0, stream>>>(xb, srcs, row_ptr, ab, N);
    gemm_k<<<(N + 63) / 64, 256, 0, stream>>>(xb, ab, wp1, b1, nullptr, h1b, N);

    // ---- layer 2 ----
    aggr_k<<<(N + 3) / 4, 256, 0, stream>>>(h1b, srcs, row_ptr, ab, N);
    gemm_k<<<(N + 63) / 64, 256, 0, stream>>>(h1b, ab, wp2, b2, out, nullptr, N);
}

// Round 5
// 274.925 us; speedup vs baseline: 2.1300x; 1.2518x over previous
//
#include <hip/hip_runtime.h>

#define D 128
typedef unsigned int uint;
typedef unsigned short ushort;
typedef __attribute__((ext_vector_type(8))) __bf16 bf16x8;
typedef __attribute__((ext_vector_type(4))) float f32x4;

// round-to-nearest-even f32 -> bf16 (bit trick)
__device__ __forceinline__ ushort f2bf(float f) {
    uint u = __float_as_uint(f);
    u += 0x7fffu + ((u >> 16) & 1u);
    return (ushort)(u >> 16);
}

// ---------------- CSR build ----------------

__global__ void hist_k(const int* __restrict__ tgt, int* __restrict__ cnt, int E) {
    int i = blockIdx.x * blockDim.x + threadIdx.x;
    if (i < E) atomicAdd(&cnt[tgt[i]], 1);
}

// two-level exclusive scan of cnt[0..n) -> row_ptr[0..n], 1024 elems per block
__global__ __launch_bounds__(256) void psum_k(const int* __restrict__ cnt,
                                              int* __restrict__ part, int n) {
    int t = threadIdx.x;
    int i = blockIdx.x * 1024 + t * 4;
    int s = 0;
    if (i + 3 < n) {
        int4 v = *reinterpret_cast<const int4*>(cnt + i);
        s = v.x + v.y + v.z + v.w;
    } else {
        for (int j = 0; j < 4; ++j) if (i + j < n) s += cnt[i + j];
    }
#pragma unroll
    for (int off = 1; off < 64; off <<= 1) s += __shfl_xor(s, off);
    __shared__ int ws[4];
    if ((t & 63) == 0) ws[t >> 6] = s;
    __syncthreads();
    if (t == 0) part[blockIdx.x] = ws[0] + ws[1] + ws[2] + ws[3];
}

__global__ void scanp_k(int* __restrict__ part, int* __restrict__ row_ptr,
                        int nb, int n) {
    int t = threadIdx.x;  // blockDim = 64, nb <= 64
    int v = (t < nb) ? part[t] : 0;
    int orig = v;
#pragma unroll
    for (int off = 1; off < 64; off <<= 1) {
        int u = __shfl_up(v, off);
        if (t >= off) v += u;
    }
    if (t < nb) part[t] = v - orig;   // exclusive block offsets
    if (t == 63) row_ptr[n] = v;      // grand total = E
}

__global__ __launch_bounds__(256) void emit_k(const int* __restrict__ cnt,
                                              const int* __restrict__ part,
                                              int* __restrict__ row_ptr, int n) {
    int t = threadIdx.x;
    int i = blockIdx.x * 1024 + t * 4;
    int c[4] = {0, 0, 0, 0};
    if (i + 3 < n) {
        int4 v = *reinterpret_cast<const int4*>(cnt + i);
        c[0] = v.x; c[1] = v.y; c[2] = v.z; c[3] = v.w;
    } else {
        for (int j = 0; j < 4; ++j) if (i + j < n) c[j] = cnt[i + j];
    }
    int s = c[0] + c[1] + c[2] + c[3];
    int v = s;
#pragma unroll
    for (int off = 1; off < 64; off <<= 1) {
        int u = __shfl_up(v, off);
        if ((t & 63) >= off) v += u;
    }
    __shared__ int wtot[4];
    if ((t & 63) == 63) wtot[t >> 6] = v;
    __syncthreads();
    int woff = 0;
    for (int w = 0; w < (t >> 6); ++w) woff += wtot[w];
    int excl = part[blockIdx.x] + woff + (v - s);
    if (i + 3 < n) {
        int4 o;
        o.x = excl;
        o.y = excl + c[0];
        o.z = excl + c[0] + c[1];
        o.w = excl + c[0] + c[1] + c[2];
        *reinterpret_cast<int4*>(row_ptr + i) = o;
    } else {
        int e = excl;
        for (int j = 0; j < 4; ++j) { if (i + j < n) row_ptr[i + j] = e; e += c[j]; }
    }
}

__global__ void fill_k(const int* __restrict__ src, const int* __restrict__ tgt,
                       const int* __restrict__ row_ptr, int* __restrict__ cur,
                       int* __restrict__ srcs, int E) {
    int i = blockIdx.x * blockDim.x + threadIdx.x;
    if (i < E) {
        int tg = tgt[i];
        int p = row_ptr[tg] + atomicAdd(&cur[tg], 1);
        srcs[p] = src[i];
    }
}

// ---------------- f32 -> bf16 convert ----------------

__global__ __launch_bounds__(256) void cvt_k(const float* __restrict__ in,
                                             ushort* __restrict__ out, int n4) {
    int i = blockIdx.x * 256 + threadIdx.x;
    if (i < n4) {
        float4 a = reinterpret_cast<const float4*>(in)[i];
        ushort4 o;
        o.x = f2bf(a.x); o.y = f2bf(a.y); o.z = f2bf(a.z); o.w = f2bf(a.w);
        reinterpret_cast<ushort4*>(out)[i] = o;
    }
}

// ---------------- W pack into MFMA B-fragment order ----------------

__global__ __launch_bounds__(256) void pack_k(const float* __restrict__ W,
                                              ushort* __restrict__ wp) {
    int idx = blockIdx.x * 256 + threadIdx.x;  // 0 .. 4095
    if (idx >= 8 * 8 * 64) return;
    int lane = idx & 63;
    int ct = (idx >> 6) & 7;
    int ks = idx >> 9;
    int col = ct * 16 + (lane & 15);
    int k0 = ks * 32 + (lane >> 4) * 8;
    ushort v[8];
#pragma unroll
    for (int e = 0; e < 8; ++e) v[e] = f2bf(W[(size_t)(k0 + e) * D + col]);
    ushort4 lo4; lo4.x = v[0]; lo4.y = v[1]; lo4.z = v[2]; lo4.w = v[3];
    ushort4 hi4; hi4.x = v[4]; hi4.y = v[5]; hi4.z = v[6]; hi4.w = v[7];
    reinterpret_cast<ushort4*>(wp + (size_t)idx * 8)[0] = lo4;
    reinterpret_cast<ushort4*>(wp + (size_t)idx * 8)[1] = hi4;
}

// ---------------- mean aggregation (CSR gather, bf16 rows, f32 accum) -------
// block = 256 threads = 4 waves, one node per wave; 8 edges in flight
// (two shfl-broadcast groups of 4), 16 lanes x 16B per row; bf16 output.

__global__ __launch_bounds__(256) void aggr_k(const ushort* __restrict__ Xb,
                                              const int* __restrict__ srcs,
                                              const int* __restrict__ row_ptr,
                                              ushort* __restrict__ aggr, int N) {
    int node = blockIdx.x * 4 + (threadIdx.x >> 6);
    if (node >= N) return;
    int lane = threadIdx.x & 63;
    int g = lane >> 4, l = lane & 15;
    int lo = row_ptr[node], hi = row_ptr[node + 1];
    float acc[8] = {0.f, 0.f, 0.f, 0.f, 0.f, 0.f, 0.f, 0.f};
    for (int base = lo; base < hi; base += 64) {
        int idx = base + lane;
        int sv = (idx < hi) ? srcs[idx] : -1;
        int cnt = min(64, hi - base);
        for (int e = 0; e < cnt; e += 8) {
            int s0 = __shfl(sv, e + g);
            int s1 = __shfl(sv, e + 4 + g);  // lanes past hi hold -1
            if (s0 >= 0) {
                const uint4 v = *reinterpret_cast<const uint4*>(Xb + (size_t)s0 * D + l * 8);
                acc[0] += __uint_as_float(v.x << 16);
                acc[1] += __uint_as_float(v.x & 0xffff0000u);
                acc[2] += __uint_as_float(v.y << 16);
                acc[3] += __uint_as_float(v.y & 0xffff0000u);
                acc[4] += __uint_as_float(v.z << 16);
                acc[5] += __uint_as_float(v.z & 0xffff0000u);
                acc[6] += __uint_as_float(v.w << 16);
                acc[7] += __uint_as_float(v.w & 0xffff0000u);
            }
            if (s1 >= 0) {
                const uint4 v = *reinterpret_cast<const uint4*>(Xb + (size_t)s1 * D + l * 8);
                acc[0] += __uint_as_float(v.x << 16);
                acc[1] += __uint_as_float(v.x & 0xffff0000u);
                acc[2] += __uint_as_float(v.y << 16);
                acc[3] += __uint_as_float(v.y & 0xffff0000u);
                acc[4] += __uint_as_float(v.z << 16);
                acc[5] += __uint_as_float(v.z & 0xffff0000u);
                acc[6] += __uint_as_float(v.w << 16);
                acc[7] += __uint_as_float(v.w & 0xffff0000u);
            }
        }
    }
#pragma unroll
    for (int j = 0; j < 8; ++j) {
        acc[j] += __shfl_xor(acc[j], 16);
        acc[j] += __shfl_xor(acc[j], 32);
    }
    if (g == 0) {
        float inv = 1.0f / fmaxf((float)(hi - lo), 1.0f);
        ushort4 o0, o1;
        o0.x = f2bf(acc[0] * inv); o0.y = f2bf(acc[1] * inv);
        o0.z = f2bf(acc[2] * inv); o0.w = f2bf(acc[3] * inv);
        o1.x = f2bf(acc[4] * inv); o1.y = f2bf(acc[5] * inv);
        o1.z = f2bf(acc[6] * inv); o1.w = f2bf(acc[7] * inv);
        ushort* dst = aggr + (size_t)node * D + l * 8;
        reinterpret_cast<ushort4*>(dst)[0] = o0;
        reinterpret_cast<ushort4*>(dst)[1] = o1;
    }
}

// ---------------- MFMA concat-GEMM + bias + relu ----------------
// C[n][128] = relu( concat(Xb,Ab)[n][256] @ W + b ),  bf16 inputs, f32 acc.
// Block = 256 thr = 4 waves. Wave w: rows [blk*64+(w&1)*32, +32),
// col tiles ct0=(w>>1)*4 .. +4 (64 cols). 8 k-steps of 32 (4 from Xb, 4 from Ab).

__global__ __launch_bounds__(256) void gemm_k(
    const ushort* __restrict__ Xb, const ushort* __restrict__ Ab,
    const ushort* __restrict__ Wp, const float* __restrict__ bias,
    float* __restrict__ outf, ushort* __restrict__ outb, int n) {
    int lane = threadIdx.x & 63;
    int w = threadIdx.x >> 6;
    int row_base = blockIdx.x * 64 + (w & 1) * 32;
    int ct0 = (w >> 1) * 4;
    int r0 = row_base + (lane & 15);
    int r1 = row_base + 16 + (lane & 15);
    if (r0 > n - 1) r0 = n - 1;
    if (r1 > n - 1) r1 = n - 1;
    int klo = (lane >> 4) * 8;

    f32x4 acc[2][4] = {};
#pragma unroll
    for (int ks = 0; ks < 8; ++ks) {
        const ushort* __restrict__ S = (ks < 4) ? Xb : Ab;
        int koff = (ks & 3) * 32 + klo;
        bf16x8 a0 = *reinterpret_cast<const bf16x8*>(S + (size_t)r0 * D + koff);
        bf16x8 a1 = *reinterpret_cast<const bf16x8*>(S + (size_t)r1 * D + koff);
        const ushort* wb = Wp + ((size_t)(ks * 8 + ct0) * 64 + lane) * 8;
#pragma unroll
        for (int c = 0; c < 4; ++c) {
            bf16x8 b = *reinterpret_cast<const bf16x8*>(wb + (size_t)c * 64 * 8);
            acc[0][c] = __builtin_amdgcn_mfma_f32_16x16x32_bf16(a0, b, acc[0][c], 0, 0, 0);
            acc[1][c] = __builtin_amdgcn_mfma_f32_16x16x32_bf16(a1, b, acc[1][c], 0, 0, 0);
        }
    }

    int cw = lane & 15;
    int rq = lane >> 4;
#pragma unroll
    for (int rt = 0; rt < 2; ++rt) {
#pragma unroll
        for (int c = 0; c < 4; ++c) {
            int col = (ct0 + c) * 16 + cw;
            float bv = bias[col];
#pragma unroll
            for (int r = 0; r < 4; ++r) {
                int node = row_base + rt * 16 + rq * 4 + r;
                if (node < n) {
                    float v = fmaxf(acc[rt][c][r] + bv, 0.f);
                    if (outf) outf[(size_t)node * D + col] = v;
                    if (outb) outb[(size_t)node * D + col] = f2bf(v);
                }
            }
        }
    }
}

extern "C" void kernel_launch(void* const* d_in, const int* in_sizes, int n_in,
                              void* d_out, int out_size, void* d_ws, size_t ws_size,
                              hipStream_t stream) {
    const float* x  = (const float*)d_in[0];
    const int*   ei = (const int*)d_in[1];
    const float* W1 = (const float*)d_in[2];
    const float* b1 = (const float*)d_in[3];
    const float* W2 = (const float*)d_in[4];
    const float* b2 = (const float*)d_in[5];
    float* out = (float*)d_out;

    const int N = in_sizes[0] / D;  // 50000
    const int E = in_sizes[1] / 2;  // 800000
    const int* src = ei;
    const int* tgt = ei + E;

    char* w = (char*)d_ws;
    auto alloc = [&](size_t bytes) -> char* {
        char* p = w;
        w += ((bytes + 255) / 256) * 256;
        return p;
    };
    int*    row_ptr = (int*)alloc((size_t)(N + 1) * 4);
    int*    cnt     = (int*)alloc((size_t)N * 4 * 2);  // cnt + cur, one memset
    int*    cur     = cnt + N;
    int*    part    = (int*)alloc(64 * 4);
    int*    srcs    = (int*)alloc((size_t)E * 4);
    ushort* xb      = (ushort*)alloc((size_t)N * D * 2);  // x   bf16
    ushort* h1b     = (ushort*)alloc((size_t)N * D * 2);  // h1  bf16
    ushort* ab      = (ushort*)alloc((size_t)N * D * 2);  // aggr bf16 (both layers)
    ushort* wp1     = (ushort*)alloc((size_t)8 * 8 * 64 * 8 * 2);
    ushort* wp2     = (ushort*)alloc((size_t)8 * 8 * 64 * 8 * 2);

    const int NB = (N + 1023) / 1024;  // 49 scan blocks

    // ---- CSR build (shared by both layers) ----
    hipMemsetAsync(cnt, 0, (size_t)N * 2 * sizeof(int), stream);
    hist_k<<<(E + 255) / 256, 256, 0, stream>>>(tgt, cnt, E);
    psum_k<<<NB, 256, 0, stream>>>(cnt, part, N);
    scanp_k<<<1, 64, 0, stream>>>(part, row_ptr, NB, N);
    emit_k<<<NB, 256, 0, stream>>>(cnt, part, row_ptr, N);
    fill_k<<<(E + 255) / 256, 256, 0, stream>>>(src, tgt, row_ptr, cur, srcs, E);

    // ---- bf16 conversions / weight packing ----
    cvt_k<<<(N * D / 4 + 255) / 256, 256, 0, stream>>>(x, xb, N * D / 4);
    pack_k<<<16, 256, 0, stream>>>(W1, wp1);
    pack_k<<<16, 256, 0, stream>>>(W2, wp2);

    // ---- layer 1 ----
    aggr_k<<<(N + 3) / 4, 256, 0, stream>>>(xb, srcs, row_ptr, ab, N);
    gemm_k<<<(N + 63) / 64, 256, 0, stream>>>(xb, ab, wp1, b1, nullptr, h1b, N);

    // ---- layer 2 ----
    aggr_k<<<(N + 3) / 4, 256, 0, stream>>>(h1b, srcs, row_ptr, ab, N);
    gemm_k<<<(N + 63) / 64, 256, 0, stream>>>(h1b, ab, wp2, b2, out, nullptr, N);
}

// Round 7
// 259.249 us; speedup vs baseline: 2.2588x; 1.0605x over previous
//
#include <hip/hip_runtime.h>

#define D 128
typedef unsigned int uint;
typedef unsigned short ushort;
typedef __attribute__((ext_vector_type(8))) __bf16 bf16x8;
typedef __attribute__((ext_vector_type(4))) float f32x4;

// round-to-nearest-even f32 -> bf16 (bit trick)
__device__ __forceinline__ ushort f2bf(float f) {
    uint u = __float_as_uint(f);
    u += 0x7fffu + ((u >> 16) & 1u);
    return (ushort)(u >> 16);
}

// ---------------- fused prep: hist + f32->bf16 cvt + W pack ----------------
// blocks [0,HB): histogram of tgt (4 edges/thread, int4 loads)
// blocks [HB,HB+CB): x f32 -> bf16 (8 elems/thread)
// blocks [HB+CB,HB+CB+32): pack W1 (16 blocks) and W2 (16 blocks)

__global__ __launch_bounds__(256) void prep_k(
    const int* __restrict__ tgt, int* __restrict__ cnt, int E, int HB,
    const float* __restrict__ x, ushort* __restrict__ xb, int n8, int CB,
    const float* __restrict__ W1, ushort* __restrict__ wp1,
    const float* __restrict__ W2, ushort* __restrict__ wp2) {
    int b = blockIdx.x;
    if (b < HB) {
        int i = (b * 256 + threadIdx.x) * 4;
        if (i + 3 < E) {
            int4 t = *reinterpret_cast<const int4*>(tgt + i);
            atomicAdd(&cnt[t.x], 1);
            atomicAdd(&cnt[t.y], 1);
            atomicAdd(&cnt[t.z], 1);
            atomicAdd(&cnt[t.w], 1);
        } else {
            for (int j = 0; j < 4; ++j)
                if (i + j < E) atomicAdd(&cnt[tgt[i + j]], 1);
        }
    } else if (b < HB + CB) {
        int i = (b - HB) * 256 + threadIdx.x;  // ushort8 group index
        if (i < n8) {
            const float4* s = reinterpret_cast<const float4*>(x) + (size_t)i * 2;
            float4 a = s[0], c = s[1];
            ushort4 o0, o1;
            o0.x = f2bf(a.x); o0.y = f2bf(a.y); o0.z = f2bf(a.z); o0.w = f2bf(a.w);
            o1.x = f2bf(c.x); o1.y = f2bf(c.y); o1.z = f2bf(c.z); o1.w = f2bf(c.w);
            reinterpret_cast<ushort4*>(xb)[(size_t)i * 2] = o0;
            reinterpret_cast<ushort4*>(xb)[(size_t)i * 2 + 1] = o1;
        }
    } else {
        int pb = b - HB - CB;  // 0..31
        const float* __restrict__ W = (pb < 16) ? W1 : W2;
        ushort* __restrict__ wp = (pb < 16) ? wp1 : wp2;
        int idx = (pb & 15) * 256 + threadIdx.x;  // 0..4095
        int lane = idx & 63;
        int ct = (idx >> 6) & 7;
        int ks = idx >> 9;
        int col = ct * 16 + (lane & 15);
        int k0 = ks * 32 + (lane >> 4) * 8;
        ushort v[8];
#pragma unroll
        for (int e = 0; e < 8; ++e) v[e] = f2bf(W[(size_t)(k0 + e) * D + col]);
        ushort4 lo4; lo4.x = v[0]; lo4.y = v[1]; lo4.z = v[2]; lo4.w = v[3];
        ushort4 hi4; hi4.x = v[4]; hi4.y = v[5]; hi4.z = v[6]; hi4.w = v[7];
        reinterpret_cast<ushort4*>(wp + (size_t)idx * 8)[0] = lo4;
        reinterpret_cast<ushort4*>(wp + (size_t)idx * 8)[1] = hi4;
    }
}

// ---------------- two-level exclusive scan ----------------

__global__ __launch_bounds__(256) void psum_k(const int* __restrict__ cnt,
                                              int* __restrict__ part, int n) {
    int t = threadIdx.x;
    int i = blockIdx.x * 1024 + t * 4;
    int s = 0;
    if (i + 3 < n) {
        int4 v = *reinterpret_cast<const int4*>(cnt + i);
        s = v.x + v.y + v.z + v.w;
    } else {
        for (int j = 0; j < 4; ++j) if (i + j < n) s += cnt[i + j];
    }
#pragma unroll
    for (int off = 1; off < 64; off <<= 1) s += __shfl_xor(s, off);
    __shared__ int ws[4];
    if ((t & 63) == 0) ws[t >> 6] = s;
    __syncthreads();
    if (t == 0) part[blockIdx.x] = ws[0] + ws[1] + ws[2] + ws[3];
}

__global__ void scanp_k(int* __restrict__ part, int* __restrict__ row_ptr,
                        int nb, int n) {
    int t = threadIdx.x;  // blockDim = 64, nb <= 64
    int v = (t < nb) ? part[t] : 0;
    int orig = v;
#pragma unroll
    for (int off = 1; off < 64; off <<= 1) {
        int u = __shfl_up(v, off);
        if (t >= off) v += u;
    }
    if (t < nb) part[t] = v - orig;   // exclusive block offsets
    if (t == 63) row_ptr[n] = v;      // grand total = E
}

// writes row_ptr AND cur (cur starts at the row base; fill bumps it)
__global__ __launch_bounds__(256) void emit_k(const int* __restrict__ cnt,
                                              const int* __restrict__ part,
                                              int* __restrict__ row_ptr,
                                              int* __restrict__ cur, int n) {
    int t = threadIdx.x;
    int i = blockIdx.x * 1024 + t * 4;
    int c[4] = {0, 0, 0, 0};
    if (i + 3 < n) {
        int4 v = *reinterpret_cast<const int4*>(cnt + i);
        c[0] = v.x; c[1] = v.y; c[2] = v.z; c[3] = v.w;
    } else {
        for (int j = 0; j < 4; ++j) if (i + j < n) c[j] = cnt[i + j];
    }
    int s = c[0] + c[1] + c[2] + c[3];
    int v = s;
#pragma unroll
    for (int off = 1; off < 64; off <<= 1) {
        int u = __shfl_up(v, off);
        if ((t & 63) >= off) v += u;
    }
    __shared__ int wtot[4];
    if ((t & 63) == 63) wtot[t >> 6] = v;
    __syncthreads();
    int woff = 0;
    for (int w = 0; w < (t >> 6); ++w) woff += wtot[w];
    int excl = part[blockIdx.x] + woff + (v - s);
    if (i + 3 < n) {
        int4 o;
        o.x = excl;
        o.y = excl + c[0];
        o.z = excl + c[0] + c[1];
        o.w = excl + c[0] + c[1] + c[2];
        *reinterpret_cast<int4*>(row_ptr + i) = o;
        *reinterpret_cast<int4*>(cur + i) = o;
    } else {
        int e = excl;
        for (int j = 0; j < 4; ++j) {
            if (i + j < n) { row_ptr[i + j] = e; cur[i + j] = e; }
            e += c[j];
        }
    }
}

// ---------------- CSR fill: 4 edges/thread, 4 atomic chains in flight -------

__global__ __launch_bounds__(256) void fill_k(const int* __restrict__ src,
                                              const int* __restrict__ tgt,
                                              int* __restrict__ cur,
                                              int* __restrict__ srcs, int E) {
    int i = (blockIdx.x * 256 + threadIdx.x) * 4;
    if (i + 3 < E) {
        int4 s = *reinterpret_cast<const int4*>(src + i);
        int4 t = *reinterpret_cast<const int4*>(tgt + i);
        int p0 = atomicAdd(&cur[t.x], 1);
        int p1 = atomicAdd(&cur[t.y], 1);
        int p2 = atomicAdd(&cur[t.z], 1);
        int p3 = atomicAdd(&cur[t.w], 1);
        srcs[p0] = s.x; srcs[p1] = s.y; srcs[p2] = s.z; srcs[p3] = s.w;
    } else {
        for (int j = 0; j < 4; ++j)
            if (i + j < E) {
                int p = atomicAdd(&cur[tgt[i + j]], 1);
                srcs[p] = src[i + j];
            }
    }
}

// ---------------- mean aggregation (CSR gather, bf16 rows, f32 accum) -------
// block = 256 threads = 4 waves, one node per wave; 16 edges per iteration
// (4 shfl-broadcast quads), clamp+mask instead of branches so the 4 uint4
// loads issue back-to-back; 16 lanes x 16B per row; bf16 output.

__global__ __launch_bounds__(256) void aggr_k(const ushort* __restrict__ Xb,
                                              const int* __restrict__ srcs,
                                              const int* __restrict__ row_ptr,
                                              ushort* __restrict__ aggr, int N) {
    int node = blockIdx.x * 4 + (threadIdx.x >> 6);
    if (node >= N) return;
    int lane = threadIdx.x & 63;
    int g = lane >> 4, l = lane & 15;
    int lo = row_ptr[node], hi = row_ptr[node + 1];
    float acc[8] = {0.f, 0.f, 0.f, 0.f, 0.f, 0.f, 0.f, 0.f};
    for (int base = lo; base < hi; base += 64) {
        int idx = base + lane;
        int sv = (idx < hi) ? srcs[idx] : -1;
        int cnt = min(64, hi - base);
        for (int e = 0; e < cnt; e += 16) {
            int ss[4];
            float m[4];
#pragma unroll
            for (int q = 0; q < 4; ++q) {
                int s = __shfl(sv, e + q * 4 + g);
                m[q] = (s >= 0) ? 1.f : 0.f;
                ss[q] = (s >= 0) ? s : 0;
            }
            uint4 vv[4];
#pragma unroll
            for (int q = 0; q < 4; ++q)
                vv[q] = *reinterpret_cast<const uint4*>(Xb + (size_t)ss[q] * D + l * 8);
#pragma unroll
            for (int q = 0; q < 4; ++q) {
                acc[0] += m[q] * __uint_as_float(vv[q].x << 16);
                acc[1] += m[q] * __uint_as_float(vv[q].x & 0xffff0000u);
                acc[2] += m[q] * __uint_as_float(vv[q].y << 16);
                acc[3] += m[q] * __uint_as_float(vv[q].y & 0xffff0000u);
                acc[4] += m[q] * __uint_as_float(vv[q].z << 16);
                acc[5] += m[q] * __uint_as_float(vv[q].z & 0xffff0000u);
                acc[6] += m[q] * __uint_as_float(vv[q].w << 16);
                acc[7] += m[q] * __uint_as_float(vv[q].w & 0xffff0000u);
            }
        }
    }
#pragma unroll
    for (int j = 0; j < 8; ++j) {
        acc[j] += __shfl_xor(acc[j], 16);
        acc[j] += __shfl_xor(acc[j], 32);
    }
    if (g == 0) {
        float inv = 1.0f / fmaxf((float)(hi - lo), 1.0f);
        ushort4 o0, o1;
        o0.x = f2bf(acc[0] * inv); o0.y = f2bf(acc[1] * inv);
        o0.z = f2bf(acc[2] * inv); o0.w = f2bf(acc[3] * inv);
        o1.x = f2bf(acc[4] * inv); o1.y = f2bf(acc[5] * inv);
        o1.z = f2bf(acc[6] * inv); o1.w = f2bf(acc[7] * inv);
        ushort* dst = aggr + (size_t)node * D + l * 8;
        reinterpret_cast<ushort4*>(dst)[0] = o0;
        reinterpret_cast<ushort4*>(dst)[1] = o1;
    }
}

// ---------------- MFMA concat-GEMM + bias + relu ----------------
// C[n][128] = relu( concat(Xb,Ab)[n][256] @ W + b ),  bf16 inputs, f32 acc.
// Block = 256 thr = 4 waves. Wave w: rows [blk*64+(w&1)*32, +32),
// col tiles ct0=(w>>1)*4 .. +4 (64 cols). 8 k-steps of 32 (4 from Xb, 4 from Ab).

__global__ __launch_bounds__(256) void gemm_k(
    const ushort* __restrict__ Xb, const ushort* __restrict__ Ab,
    const ushort* __restrict__ Wp, const float* __restrict__ bias,
    float* __restrict__ outf, ushort* __restrict__ outb, int n) {
    int lane = threadIdx.x & 63;
    int w = threadIdx.x >> 6;
    int row_base = blockIdx.x * 64 + (w & 1) * 32;
    int ct0 = (w >> 1) * 4;
    int r0 = row_base + (lane & 15);
    int r1 = row_base + 16 + (lane & 15);
    if (r0 > n - 1) r0 = n - 1;
    if (r1 > n - 1) r1 = n - 1;
    int klo = (lane >> 4) * 8;

    f32x4 acc[2][4] = {};
#pragma unroll
    for (int ks = 0; ks < 8; ++ks) {
        const ushort* __restrict__ S = (ks < 4) ? Xb : Ab;
        int koff = (ks & 3) * 32 + klo;
        bf16x8 a0 = *reinterpret_cast<const bf16x8*>(S + (size_t)r0 * D + koff);
        bf16x8 a1 = *reinterpret_cast<const bf16x8*>(S + (size_t)r1 * D + koff);
        const ushort* wb = Wp + ((size_t)(ks * 8 + ct0) * 64 + lane) * 8;
#pragma unroll
        for (int c = 0; c < 4; ++c) {
            bf16x8 b = *reinterpret_cast<const bf16x8*>(wb + (size_t)c * 64 * 8);
            acc[0][c] = __builtin_amdgcn_mfma_f32_16x16x32_bf16(a0, b, acc[0][c], 0, 0, 0);
            acc[1][c] = __builtin_amdgcn_mfma_f32_16x16x32_bf16(a1, b, acc[1][c], 0, 0, 0);
        }
    }

    int cw = lane & 15;
    int rq = lane >> 4;
#pragma unroll
    for (int rt = 0; rt < 2; ++rt) {
#pragma unroll
        for (int c = 0; c < 4; ++c) {
            int col = (ct0 + c) * 16 + cw;
            float bv = bias[col];
#pragma unroll
            for (int r = 0; r < 4; ++r) {
                int node = row_base + rt * 16 + rq * 4 + r;
                if (node < n) {
                    float v = fmaxf(acc[rt][c][r] + bv, 0.f);
                    if (outf) outf[(size_t)node * D + col] = v;
                    if (outb) outb[(size_t)node * D + col] = f2bf(v);
                }
            }
        }
    }
}

extern "C" void kernel_launch(void* const* d_in, const int* in_sizes, int n_in,
                              void* d_out, int out_size, void* d_ws, size_t ws_size,
                              hipStream_t stream) {
    const float* x  = (const float*)d_in[0];
    const int*   ei = (const int*)d_in[1];
    const float* W1 = (const float*)d_in[2];
    const float* b1 = (const float*)d_in[3];
    const float* W2 = (const float*)d_in[4];
    const float* b2 = (const float*)d_in[5];
    float* out = (float*)d_out;

    const int N = in_sizes[0] / D;  // 50000
    const int E = in_sizes[1] / 2;  // 800000
    const int* src = ei;
    const int* tgt = ei + E;

    char* w = (char*)d_ws;
    auto alloc = [&](size_t bytes) -> char* {
        char* p = w;
        w += ((bytes + 255) / 256) * 256;
        return p;
    };
    int*    row_ptr = (int*)alloc((size_t)(N + 1) * 4);
    int*    cnt     = (int*)alloc((size_t)N * 4);
    int*    cur     = (int*)alloc((size_t)N * 4);
    int*    part    = (int*)alloc(64 * 4);
    int*    srcs    = (int*)alloc((size_t)E * 4);
    ushort* xb      = (ushort*)alloc((size_t)N * D * 2);  // x   bf16
    ushort* h1b     = (ushort*)alloc((size_t)N * D * 2);  // h1  bf16
    ushort* ab      = (ushort*)alloc((size_t)N * D * 2);  // aggr bf16 (both layers)
    ushort* wp1     = (ushort*)alloc((size_t)8 * 8 * 64 * 8 * 2);
    ushort* wp2     = (ushort*)alloc((size_t)8 * 8 * 64 * 8 * 2);

    const int NB = (N + 1023) / 1024;        // 49 scan blocks
    const int HB = (E + 1023) / 1024;        // 782 hist/fill blocks (4 edges/thr)
    const int n8 = N * D / 8;                // ushort8 groups in x
    const int CB = (n8 + 255) / 256;         // 3125 cvt blocks

    // cnt must be zero before prep_k's histogram
    hipMemsetAsync(cnt, 0, (size_t)N * sizeof(int), stream);

    // ---- fused prep: hist + cvt + pack (one dispatch) ----
    prep_k<<<HB + CB + 32, 256, 0, stream>>>(tgt, cnt, E, HB,
                                             x, xb, n8, CB,
                                             W1, wp1, W2, wp2);

    // ---- scan + CSR fill ----
    psum_k<<<NB, 256, 0, stream>>>(cnt, part, N);
    scanp_k<<<1, 64, 0, stream>>>(part, row_ptr, NB, N);
    emit_k<<<NB, 256, 0, stream>>>(cnt, part, row_ptr, cur, N);
    fill_k<<<HB, 256, 0, stream>>>(src, tgt, cur, srcs, E);

    // ---- layer 1 ----
    aggr_k<<<(N + 3) / 4, 256, 0, stream>>>(xb, srcs, row_ptr, ab, N);
    gemm_k<<<(N + 63) / 64, 256, 0, stream>>>(xb, ab, wp1, b1, nullptr, h1b, N);

    // ---- layer 2 ----
    aggr_k<<<(N + 3) / 4, 256, 0, stream>>>(h1b, srcs, row_ptr, ab, N);
    gemm_k<<<(N + 63) / 64, 256, 0, stream>>>(h1b, ab, wp2, b2, out, nullptr, N);
}